// Round 7
// baseline (566.678 us; speedup 1.0000x reference)
//
#include <hip/hip_runtime.h>
#include <hip/hip_bf16.h>
#include <math.h>
#include <stdint.h>

#define D_MODEL 1024
#define NH 16
#define HD 64
#define BATCH 4
#define SEQ 2048

typedef unsigned short u16;
typedef __attribute__((ext_vector_type(2))) unsigned short u16x2;
typedef __attribute__((ext_vector_type(4))) unsigned short u16x4;
typedef __attribute__((ext_vector_type(8))) unsigned short u16x8;
typedef __attribute__((ext_vector_type(8))) short short8;
typedef __attribute__((ext_vector_type(4))) float f32x4;

// ---------------------------------------------------------------------------
// fp32 <-> bf16 (RNE). f2bf uses the HIP HW cast (m240: scalar cast > hand asm).
// ---------------------------------------------------------------------------
__device__ __forceinline__ u16 f2bf(float f) {
  __hip_bfloat16 h = __float2bfloat16(f);
  u16 u;
  __builtin_memcpy(&u, &h, sizeof(u));
  return u;
}
__device__ __forceinline__ float bf2f(u16 h) {
  return __uint_as_float(((uint32_t)h) << 16);
}

// global -> LDS direct copy, 16B per lane (lds dest = wave-uniform base + lane*16)
__device__ __forceinline__ void gload_lds16(const void* g, void* l) {
  auto gp = (const __attribute__((address_space(1))) uint32_t*)(uintptr_t)(g);
  auto lp = (__attribute__((address_space(3))) uint32_t*)(uintptr_t)(l);
  __builtin_amdgcn_global_load_lds(gp, lp, 16, 0, 0);
}

// ---------------------------------------------------------------------------
// split fp32 -> bf16 hi/lo   (lo = bf16(x - f32(hi)))
// ---------------------------------------------------------------------------
__launch_bounds__(256)
__global__ void split_hl(const float* __restrict__ in, u16* __restrict__ hi,
                         u16* __restrict__ lo, int n4) {
  int i = blockIdx.x * blockDim.x + threadIdx.x;
  const int stride = gridDim.x * blockDim.x;
  for (; i < n4; i += stride) {
    float4 v = ((const float4*)in)[i];
    u16x4 h, l4;
    h.x = f2bf(v.x); l4.x = f2bf(v.x - bf2f(h.x));
    h.y = f2bf(v.y); l4.y = f2bf(v.y - bf2f(h.y));
    h.z = f2bf(v.z); l4.z = f2bf(v.z - bf2f(h.z));
    h.w = f2bf(v.w); l4.w = f2bf(v.w - bf2f(h.w));
    ((u16x4*)hi)[i] = h;
    ((u16x4*)lo)[i] = l4;
  }
}

// ---------------------------------------------------------------------------
// C[M,N] = A[M,K] @ B[N,K]^T, split-bf16 x3 MFMA (fp32-accurate):
//   C = Ahi*Bhi + Ahi*Blo + Alo*Bhi   (drops only lo*lo, ~2^-16 rel)
// 128x128 tile, BK=32, 4 waves (m97 structure). SPLIT=1: emit hi/lo bf16.
// FROZEN (round-5/6 counters: at ~m97-structure ceiling).
// ---------------------------------------------------------------------------
template <int SPLIT>
__launch_bounds__(256)
__global__ void gemm_nt_bf16x3(const u16* __restrict__ Ahi, const u16* __restrict__ Alo,
                               const u16* __restrict__ Bhi, const u16* __restrict__ Blo,
                               float* __restrict__ C, u16* __restrict__ Chi,
                               u16* __restrict__ Clo, int M, int N, int K) {
  __shared__ u16 sAh[128][32];
  __shared__ u16 sAl[128][32];
  __shared__ u16 sBh[128][32];
  __shared__ u16 sBl[128][32];

  const int tid = threadIdx.x;
  const int w = tid >> 6;
  const int l = tid & 63;
  const int bm = blockIdx.y * 128;
  const int bn = blockIdx.x * 128;
  const int wr = (w >> 1) * 64;
  const int wc = (w & 1) * 64;

  const int lr = l >> 2;
  const int lco = (l & 3) << 3;

  const u16* gAh = Ahi + (size_t)bm * K;
  const u16* gAl = Alo + (size_t)bm * K;
  const u16* gBh = Bhi + (size_t)bn * K;
  const u16* gBl = Blo + (size_t)bn * K;

  f32x4 acc[4][4] = {};

  const int fr = l & 15;
  const int fko = (l >> 4) << 3;

  for (int k0 = 0; k0 < K; k0 += 32) {
    __syncthreads();
#pragma unroll
    for (int i = 0; i < 2; ++i) {
      const int bo = (w + 4 * i) << 10;
      const int r = (bo >> 6) + lr;
      const size_t go = (size_t)r * K + k0 + lco;
      gload_lds16(gAh + go, (char*)&sAh[0][0] + bo);
      gload_lds16(gAl + go, (char*)&sAl[0][0] + bo);
      gload_lds16(gBh + go, (char*)&sBh[0][0] + bo);
      gload_lds16(gBl + go, (char*)&sBl[0][0] + bo);
    }
    __syncthreads();

    short8 ah[4], al[4], bh[4], bl[4];
#pragma unroll
    for (int m = 0; m < 4; ++m) {
      ah[m] = *(const short8*)&sAh[wr + m * 16 + fr][fko];
      al[m] = *(const short8*)&sAl[wr + m * 16 + fr][fko];
    }
#pragma unroll
    for (int n = 0; n < 4; ++n) {
      bh[n] = *(const short8*)&sBh[wc + n * 16 + fr][fko];
      bl[n] = *(const short8*)&sBl[wc + n * 16 + fr][fko];
    }
#pragma unroll
    for (int m = 0; m < 4; ++m)
#pragma unroll
      for (int n = 0; n < 4; ++n) {
        acc[m][n] = __builtin_amdgcn_mfma_f32_16x16x32_bf16(ah[m], bh[n], acc[m][n], 0, 0, 0);
        acc[m][n] = __builtin_amdgcn_mfma_f32_16x16x32_bf16(ah[m], bl[n], acc[m][n], 0, 0, 0);
        acc[m][n] = __builtin_amdgcn_mfma_f32_16x16x32_bf16(al[m], bh[n], acc[m][n], 0, 0, 0);
      }
  }

  // C/D layout: col=lane&15, row=(lane>>4)*4 + j  [m89 verified]
#pragma unroll
  for (int m = 0; m < 4; ++m) {
    const int row0 = bm + wr + m * 16 + ((l >> 4) << 2);
#pragma unroll
    for (int n = 0; n < 4; ++n) {
      const int col = bn + wc + n * 16 + fr;
      f32x4 v = acc[m][n];
      if constexpr (SPLIT) {
#pragma unroll
        for (int j = 0; j < 4; ++j) {
          const size_t idx = (size_t)(row0 + j) * N + col;
          u16 hh = f2bf(v[j]);
          Chi[idx] = hh;
          Clo[idx] = f2bf(v[j] - bf2f(hh));
        }
      } else {
        float* cp = C + (size_t)row0 * N + col;
#pragma unroll
        for (int j = 0; j < 4; ++j) cp[(size_t)j * N] = v[j];
      }
    }
  }
}

// ---------------------------------------------------------------------------
// Attention v3: paired q-tiles (pr, 31-pr); shared K/V FRAGMENT loads on
// co-active tiles; HW bf16 casts; exp2-domain softmax. Math = round-4 design.
// ---------------------------------------------------------------------------
#define SC2 0.18033688011112042f  /* 0.125 * log2(e) */

struct AttnCtx {
  short8 Qh[2], Ql[2];
  f32x4 acc[4];
  float m_run, l_run;
  int q0w;
};

__device__ __forceinline__ void ctx_init(AttnCtx& C, const u16* __restrict__ qkvh,
                                         const u16* __restrict__ qkvl, size_t base,
                                         int q0w, int g, int q16) {
  C.q0w = q0w;
  const size_t qoff = base + (size_t)(q0w + q16) * (3 * D_MODEL);
#pragma unroll
  for (int dh = 0; dh < 2; ++dh) {
    C.Qh[dh] = *(const short8*)(qkvh + qoff + dh * 32 + g * 8);
    C.Ql[dh] = *(const short8*)(qkvl + qoff + dh * 32 + g * 8);
  }
#pragma unroll
  for (int n = 0; n < 4; ++n) C.acc[n] = f32x4{0.f, 0.f, 0.f, 0.f};
  C.m_run = -1e30f;
  C.l_run = 0.f;
}

// mask+scale (exp2 domain), online-softmax update, P hi/lo store, acc rescale
__device__ __forceinline__ void softmax_store(AttnCtx& C, const f32x4 S[2], int j0,
                                              int g, int q16, char* PhS, char* PlS) {
  const int qg = C.q0w + q16;
  float p[8];
  float mx = -1e30f;
#pragma unroll
  for (int t2 = 0; t2 < 2; ++t2)
#pragma unroll
    for (int j = 0; j < 4; ++j) {
      const int kg = j0 + 16 * t2 + 4 * g + j;
      float s = (kg <= qg) ? S[t2][j] * SC2 : -1e30f;
      p[t2 * 4 + j] = s;
      mx = fmaxf(mx, s);
    }
  mx = fmaxf(mx, __shfl_xor(mx, 16));
  mx = fmaxf(mx, __shfl_xor(mx, 32));
  const float m_new = fmaxf(C.m_run, mx);
  float sum = 0.f;
#pragma unroll
  for (int i = 0; i < 8; ++i) { p[i] = exp2f(p[i] - m_new); sum += p[i]; }
  sum += __shfl_xor(sum, 16);
  sum += __shfl_xor(sum, 32);
  const float alpha = exp2f(C.m_run - m_new);
  C.m_run = m_new;
  C.l_run = C.l_run * alpha + sum;
#pragma unroll
  for (int t2 = 0; t2 < 2; ++t2) {
    u16x4 ph, pl;
#pragma unroll
    for (int j = 0; j < 4; ++j) {
      float v = p[t2 * 4 + j];
      ph[j] = f2bf(v);
      pl[j] = f2bf(v - bf2f(ph[j]));
    }
    const int off = q16 * 80 + (16 * t2 + 4 * g) * 2;
    *(u16x4*)(PhS + off) = ph;
    *(u16x4*)(PlS + off) = pl;
  }
  float al4[4];
#pragma unroll
  for (int j = 0; j < 4; ++j) al4[j] = __shfl(alpha, 4 * g + j);
#pragma unroll
  for (int n = 0; n < 4; ++n) {
    f32x4 t = C.acc[n];
    t[0] *= al4[0]; t[1] *= al4[1]; t[2] *= al4[2]; t[3] *= al4[3];
    C.acc[n] = t;
  }
}

// both contexts active on this tile: share KA and VB fragment loads
__device__ __forceinline__ void process_pair(AttnCtx& A, AttnCtx& B, int j0, int g,
                                             int q16, const char* KhB, const char* KlB,
                                             const char* VhB, const char* VlB,
                                             char* PhW, char* PlW) {
  f32x4 SB[2] = {}, SA[2] = {};
#pragma unroll
  for (int t2 = 0; t2 < 2; ++t2) {  // t2-split bounds KA liveness to 16 VGPR
    short8 KAh[2], KAl[2];
#pragma unroll
    for (int dh = 0; dh < 2; ++dh) {
      const int off = (16 * t2 + q16) * 128 + ((dh * 64 + g * 16) ^ ((q16 & 7) << 4));
      KAh[dh] = *(const short8*)(KhB + off);
      KAl[dh] = *(const short8*)(KlB + off);
    }
#pragma unroll
    for (int dh = 0; dh < 2; ++dh) {
      SB[t2] = __builtin_amdgcn_mfma_f32_16x16x32_bf16(KAh[dh], B.Qh[dh], SB[t2], 0, 0, 0);
      SB[t2] = __builtin_amdgcn_mfma_f32_16x16x32_bf16(KAh[dh], B.Ql[dh], SB[t2], 0, 0, 0);
      SB[t2] = __builtin_amdgcn_mfma_f32_16x16x32_bf16(KAl[dh], B.Qh[dh], SB[t2], 0, 0, 0);
      SA[t2] = __builtin_amdgcn_mfma_f32_16x16x32_bf16(KAh[dh], A.Qh[dh], SA[t2], 0, 0, 0);
      SA[t2] = __builtin_amdgcn_mfma_f32_16x16x32_bf16(KAh[dh], A.Ql[dh], SA[t2], 0, 0, 0);
      SA[t2] = __builtin_amdgcn_mfma_f32_16x16x32_bf16(KAl[dh], A.Qh[dh], SA[t2], 0, 0, 0);
    }
  }
  softmax_store(B, SB, j0, g, q16, PhW, PlW);               // slot 0
  softmax_store(A, SA, j0, g, q16, PhW + 1280, PlW + 1280); // slot 1
  const short8 PBh = *(const short8*)(PhW + q16 * 80 + g * 16);
  const short8 PBl = *(const short8*)(PlW + q16 * 80 + g * 16);
  const short8 PAh = *(const short8*)(PhW + 1280 + q16 * 80 + g * 16);
  const short8 PAl = *(const short8*)(PlW + 1280 + q16 * 80 + g * 16);
#pragma unroll
  for (int n = 0; n < 4; ++n) {
    const int off = (16 * n + q16) * 80 + g * 16;
    const short8 VBh = *(const short8*)(VhB + off);
    const short8 VBl = *(const short8*)(VlB + off);
    B.acc[n] = __builtin_amdgcn_mfma_f32_16x16x32_bf16(PBh, VBh, B.acc[n], 0, 0, 0);
    B.acc[n] = __builtin_amdgcn_mfma_f32_16x16x32_bf16(PBh, VBl, B.acc[n], 0, 0, 0);
    B.acc[n] = __builtin_amdgcn_mfma_f32_16x16x32_bf16(PBl, VBh, B.acc[n], 0, 0, 0);
    A.acc[n] = __builtin_amdgcn_mfma_f32_16x16x32_bf16(PAh, VBh, A.acc[n], 0, 0, 0);
    A.acc[n] = __builtin_amdgcn_mfma_f32_16x16x32_bf16(PAh, VBl, A.acc[n], 0, 0, 0);
    A.acc[n] = __builtin_amdgcn_mfma_f32_16x16x32_bf16(PAl, VBh, A.acc[n], 0, 0, 0);
  }
}

// only ctx B active on this tile
__device__ __forceinline__ void process_single(AttnCtx& B, int j0, int g, int q16,
                                               const char* KhB, const char* KlB,
                                               const char* VhB, const char* VlB,
                                               char* PhW, char* PlW) {
  f32x4 SB[2] = {};
#pragma unroll
  for (int t2 = 0; t2 < 2; ++t2) {
    short8 KAh[2], KAl[2];
#pragma unroll
    for (int dh = 0; dh < 2; ++dh) {
      const int off = (16 * t2 + q16) * 128 + ((dh * 64 + g * 16) ^ ((q16 & 7) << 4));
      KAh[dh] = *(const short8*)(KhB + off);
      KAl[dh] = *(const short8*)(KlB + off);
    }
#pragma unroll
    for (int dh = 0; dh < 2; ++dh) {
      SB[t2] = __builtin_amdgcn_mfma_f32_16x16x32_bf16(KAh[dh], B.Qh[dh], SB[t2], 0, 0, 0);
      SB[t2] = __builtin_amdgcn_mfma_f32_16x16x32_bf16(KAh[dh], B.Ql[dh], SB[t2], 0, 0, 0);
      SB[t2] = __builtin_amdgcn_mfma_f32_16x16x32_bf16(KAl[dh], B.Qh[dh], SB[t2], 0, 0, 0);
    }
  }
  softmax_store(B, SB, j0, g, q16, PhW, PlW);
  const short8 PBh = *(const short8*)(PhW + q16 * 80 + g * 16);
  const short8 PBl = *(const short8*)(PlW + q16 * 80 + g * 16);
#pragma unroll
  for (int n = 0; n < 4; ++n) {
    const int off = (16 * n + q16) * 80 + g * 16;
    const short8 VBh = *(const short8*)(VhB + off);
    const short8 VBl = *(const short8*)(VlB + off);
    B.acc[n] = __builtin_amdgcn_mfma_f32_16x16x32_bf16(PBh, VBh, B.acc[n], 0, 0, 0);
    B.acc[n] = __builtin_amdgcn_mfma_f32_16x16x32_bf16(PBh, VBl, B.acc[n], 0, 0, 0);
    B.acc[n] = __builtin_amdgcn_mfma_f32_16x16x32_bf16(PBl, VBh, B.acc[n], 0, 0, 0);
  }
}

__device__ __forceinline__ void ctx_epilogue(const AttnCtx& C, u16* __restrict__ Ohi,
                                             u16* __restrict__ Olo, int b, int h,
                                             int g, int q16) {
  float inv[4];
#pragma unroll
  for (int j = 0; j < 4; ++j) inv[j] = 1.0f / __shfl(C.l_run, 4 * g + j);
#pragma unroll
  for (int n = 0; n < 4; ++n)
#pragma unroll
    for (int j = 0; j < 4; ++j) {
      const size_t idx =
          ((size_t)b * SEQ + C.q0w + 4 * g + j) * D_MODEL + h * HD + n * 16 + q16;
      const float v = C.acc[n][j] * inv[j];
      const u16 hh = f2bf(v);
      Ohi[idx] = hh;
      Olo[idx] = f2bf(v - bf2f(hh));
    }
}

__launch_bounds__(256)
__global__ void attn_mfma(const u16* __restrict__ qkvh, const u16* __restrict__ qkvl,
                          u16* __restrict__ Ohi, u16* __restrict__ Olo) {
  __shared__ u16 Kh[32][64], Kl[32][64];
  __shared__ u16 Vh[64][40], Vl[64][40];
  __shared__ u16 Ph[4][2][16][40], Pl[4][2][16][40];  // per-wave, 2 slots (B,A)

  const int tid = threadIdx.x;
  const int w = tid >> 6, l = tid & 63;
  const int g = l >> 4, q16 = l & 15;
  const int pr = blockIdx.x;            // pair index 0..15
  const int qbA = pr, qbB = 31 - pr;    // balanced pairing: constant total work
  const int bh = blockIdx.y;
  const int b = bh >> 4, h = bh & 15;
  const size_t base = (size_t)b * SEQ * (3 * D_MODEL) + h * HD;

  char* KhB = (char*)&Kh[0][0];
  char* KlB = (char*)&Kl[0][0];
  char* VhB = (char*)&Vh[0][0];
  char* VlB = (char*)&Vl[0][0];
  char* PhW = (char*)&Ph[w][0][0][0];
  char* PlW = (char*)&Pl[w][0][0][0];

  AttnCtx A, B;
  ctx_init(A, qkvh, qkvl, base, qbA * 64 + w * 16, g, q16);
  ctx_init(B, qkvh, qkvl, base, qbB * 64 + w * 16, g, q16);

  // staging geometry
  const int sk = tid >> 3, sd0 = (tid & 7) * 8;          // K: row sk, d sd0..+7
  const int vd0 = (tid & 31) * 2, vk0 = (tid >> 5) * 4;  // V: d {vd0,vd0+1}, k vk0..+3
  u16x8 kh_r, kl_r;
  u16x2 vh_r[4], vl_r[4];

  auto loadKV = [&](int j0) {
    const size_t srcK = base + D_MODEL + (size_t)(j0 + sk) * (3 * D_MODEL) + sd0;
    kh_r = *(const u16x8*)(qkvh + srcK);
    kl_r = *(const u16x8*)(qkvl + srcK);
    const size_t srcV = base + 2 * D_MODEL + (size_t)(j0 + vk0) * (3 * D_MODEL) + vd0;
#pragma unroll
    for (int r = 0; r < 4; ++r) {
      vh_r[r] = *(const u16x2*)(qkvh + srcV + (size_t)r * (3 * D_MODEL));
      vl_r[r] = *(const u16x2*)(qkvl + srcV + (size_t)r * (3 * D_MODEL));
    }
  };
  auto writeKV = [&]() {
    const int offK = sk * 128 + ((sd0 * 2) ^ ((sk & 7) << 4));  // XOR swizzle
    *(u16x8*)(KhB + offK) = kh_r;
    *(u16x8*)(KlB + offK) = kl_r;
#pragma unroll
    for (int j = 0; j < 2; ++j) {  // transpose: V^T[d][k]
      u16x4 th, tl;
      th[0] = vh_r[0][j]; th[1] = vh_r[1][j]; th[2] = vh_r[2][j]; th[3] = vh_r[3][j];
      tl[0] = vl_r[0][j]; tl[1] = vl_r[1][j]; tl[2] = vl_r[2][j]; tl[3] = vl_r[3][j];
      const int off = (vd0 + j) * 80 + vk0 * 2;
      *(u16x4*)(VhB + off) = th;
      *(u16x4*)(VlB + off) = tl;
    }
  };

  const int ktiles = 2 * qbB + 2;
  loadKV(0);
  for (int kt = 0; kt < ktiles; ++kt) {
    const int j0 = kt * 32;
    __syncthreads();                       // prior tile's LDS reads done
    writeKV();                             // regs -> LDS
    __syncthreads();                       // tile visible
    if (kt + 1 < ktiles) loadKV((kt + 1) * 32);  // prefetch next (overlaps compute)
    const bool actA = j0 <= A.q0w + 15;    // wave-uniform; actA implies actB
    const bool actB = j0 <= B.q0w + 15;
    if (actA)      process_pair(A, B, j0, g, q16, KhB, KlB, VhB, VlB, PhW, PlW);
    else if (actB) process_single(B, j0, g, q16, KhB, KlB, VhB, VlB, PhW, PlW);
  }

  ctx_epilogue(B, Ohi, Olo, b, h, g, q16);
  ctx_epilogue(A, Ohi, Olo, b, h, g, q16);
}

// ---------------------------------------------------------------------------
extern "C" void kernel_launch(void* const* d_in, const int* in_sizes, int n_in,
                              void* d_out, int out_size, void* d_ws, size_t ws_size,
                              hipStream_t stream) {
  const float* x    = (const float*)d_in[0];   // [4,2048,1024]
  const float* Wqkv = (const float*)d_in[1];   // [3072,1024]
  const float* Wout = (const float*)d_in[2];   // [1024,1024]
  float* out = (float*)d_out;                  // [4,2048,1024]

  const int M = BATCH * SEQ;                   // 8192
  const int N1 = 3 * D_MODEL;                  // 3072
  const size_t MB = 1024 * 1024;

  // workspace layout (144 MB, with aliasing):
  char* ws = (char*)d_ws;
  u16* qkvh = (u16*)(ws);                      // [0,48)   MB
  u16* qkvl = (u16*)(ws + 48 * MB);            // [48,96)
  u16* xhi  = (u16*)(ws + 96 * MB);            // [96,112)
  u16* xlo  = (u16*)(ws + 112 * MB);           // [112,128)
  u16* whi  = (u16*)(ws + 128 * MB);           // [128,134)
  u16* wlo  = (u16*)(ws + 134 * MB);           // [134,140)
  u16* ohi  = (u16*)(ws + 140 * MB);           // [140,142)
  u16* olo  = (u16*)(ws + 142 * MB);           // [142,144)
  // attention output hi/lo alias xhi/xlo (dead after GEMM1):
  u16* ahi  = (u16*)(ws + 96 * MB);
  u16* alo  = (u16*)(ws + 112 * MB);

  // 1) split inputs to bf16 hi/lo
  split_hl<<<2048, 256, 0, stream>>>(x,    xhi, xlo, M * D_MODEL / 4);
  split_hl<<<2048, 256, 0, stream>>>(Wqkv, whi, wlo, N1 * D_MODEL / 4);
  split_hl<<<1024, 256, 0, stream>>>(Wout, ohi, olo, D_MODEL * D_MODEL / 4);

  // 2) qkv(hi/lo) = x @ Wqkv^T   (emit split directly from fp32 accumulator)
  gemm_nt_bf16x3<1><<<dim3(N1 / 128, M / 128), 256, 0, stream>>>(
      xhi, xlo, whi, wlo, nullptr, qkvh, qkvl, M, N1, D_MODEL);

  // 3) causal MFMA flash attention (paired q-tiles, shared fragment loads)
  attn_mfma<<<dim3(SEQ / 128, BATCH * NH), 256, 0, stream>>>(qkvh, qkvl, ahi, alo);

  // 4) out = attn @ Wout^T  (fp32 out)
  gemm_nt_bf16x3<0><<<dim3(D_MODEL / 128, M / 128), 256, 0, stream>>>(
      ahi, alo, ohi, olo, out, nullptr, nullptr, M, D_MODEL, D_MODEL);
}

// Round 8
// 546.658 us; speedup vs baseline: 1.0366x; 1.0366x over previous
//
#include <hip/hip_runtime.h>
#include <hip/hip_bf16.h>
#include <math.h>
#include <stdint.h>

#define D_MODEL 1024
#define NH 16
#define HD 64
#define BATCH 4
#define SEQ 2048

typedef unsigned short u16;
typedef __attribute__((ext_vector_type(2))) unsigned short u16x2;
typedef __attribute__((ext_vector_type(4))) unsigned short u16x4;
typedef __attribute__((ext_vector_type(8))) unsigned short u16x8;
typedef __attribute__((ext_vector_type(8))) short short8;
typedef __attribute__((ext_vector_type(4))) float f32x4;

// ---------------------------------------------------------------------------
// fp32 <-> bf16 (RNE)
// ---------------------------------------------------------------------------
__device__ __forceinline__ u16 f2bf(float f) {
  __hip_bfloat16 h = __float2bfloat16(f);
  u16 u;
  __builtin_memcpy(&u, &h, sizeof(u));
  return u;
}
__device__ __forceinline__ float bf2f(u16 h) {
  return __uint_as_float(((uint32_t)h) << 16);
}

// global -> LDS direct copy, 16B per lane (lds dest = wave-uniform base + lane*16)
__device__ __forceinline__ void gload_lds16(const void* g, void* l) {
  auto gp = (const __attribute__((address_space(1))) uint32_t*)(uintptr_t)(g);
  auto lp = (__attribute__((address_space(3))) uint32_t*)(uintptr_t)(l);
  __builtin_amdgcn_global_load_lds(gp, lp, 16, 0, 0);
}

// ---------------------------------------------------------------------------
// split fp32 -> bf16 hi/lo   (lo = bf16(x - f32(hi)))
// ---------------------------------------------------------------------------
__launch_bounds__(256)
__global__ void split_hl(const float* __restrict__ in, u16* __restrict__ hi,
                         u16* __restrict__ lo, int n4) {
  int i = blockIdx.x * blockDim.x + threadIdx.x;
  const int stride = gridDim.x * blockDim.x;
  for (; i < n4; i += stride) {
    float4 v = ((const float4*)in)[i];
    u16x4 h, l4;
    h.x = f2bf(v.x); l4.x = f2bf(v.x - bf2f(h.x));
    h.y = f2bf(v.y); l4.y = f2bf(v.y - bf2f(h.y));
    h.z = f2bf(v.z); l4.z = f2bf(v.z - bf2f(h.z));
    h.w = f2bf(v.w); l4.w = f2bf(v.w - bf2f(h.w));
    ((u16x4*)hi)[i] = h;
    ((u16x4*)lo)[i] = l4;
  }
}

// ---------------------------------------------------------------------------
// C[M,N] = A[M,K] @ B[N,K]^T, split-bf16 x3 MFMA (fp32-accurate). FROZEN.
// ---------------------------------------------------------------------------
template <int SPLIT>
__launch_bounds__(256)
__global__ void gemm_nt_bf16x3(const u16* __restrict__ Ahi, const u16* __restrict__ Alo,
                               const u16* __restrict__ Bhi, const u16* __restrict__ Blo,
                               float* __restrict__ C, u16* __restrict__ Chi,
                               u16* __restrict__ Clo, int M, int N, int K) {
  __shared__ u16 sAh[128][32];
  __shared__ u16 sAl[128][32];
  __shared__ u16 sBh[128][32];
  __shared__ u16 sBl[128][32];

  const int tid = threadIdx.x;
  const int w = tid >> 6;
  const int l = tid & 63;
  const int bm = blockIdx.y * 128;
  const int bn = blockIdx.x * 128;
  const int wr = (w >> 1) * 64;
  const int wc = (w & 1) * 64;

  const int lr = l >> 2;
  const int lco = (l & 3) << 3;

  const u16* gAh = Ahi + (size_t)bm * K;
  const u16* gAl = Alo + (size_t)bm * K;
  const u16* gBh = Bhi + (size_t)bn * K;
  const u16* gBl = Blo + (size_t)bn * K;

  f32x4 acc[4][4] = {};

  const int fr = l & 15;
  const int fko = (l >> 4) << 3;

  for (int k0 = 0; k0 < K; k0 += 32) {
    __syncthreads();
#pragma unroll
    for (int i = 0; i < 2; ++i) {
      const int bo = (w + 4 * i) << 10;
      const int r = (bo >> 6) + lr;
      const size_t go = (size_t)r * K + k0 + lco;
      gload_lds16(gAh + go, (char*)&sAh[0][0] + bo);
      gload_lds16(gAl + go, (char*)&sAl[0][0] + bo);
      gload_lds16(gBh + go, (char*)&sBh[0][0] + bo);
      gload_lds16(gBl + go, (char*)&sBl[0][0] + bo);
    }
    __syncthreads();

    short8 ah[4], al[4], bh[4], bl[4];
#pragma unroll
    for (int m = 0; m < 4; ++m) {
      ah[m] = *(const short8*)&sAh[wr + m * 16 + fr][fko];
      al[m] = *(const short8*)&sAl[wr + m * 16 + fr][fko];
    }
#pragma unroll
    for (int n = 0; n < 4; ++n) {
      bh[n] = *(const short8*)&sBh[wc + n * 16 + fr][fko];
      bl[n] = *(const short8*)&sBl[wc + n * 16 + fr][fko];
    }
#pragma unroll
    for (int m = 0; m < 4; ++m)
#pragma unroll
      for (int n = 0; n < 4; ++n) {
        acc[m][n] = __builtin_amdgcn_mfma_f32_16x16x32_bf16(ah[m], bh[n], acc[m][n], 0, 0, 0);
        acc[m][n] = __builtin_amdgcn_mfma_f32_16x16x32_bf16(ah[m], bl[n], acc[m][n], 0, 0, 0);
        acc[m][n] = __builtin_amdgcn_mfma_f32_16x16x32_bf16(al[m], bh[n], acc[m][n], 0, 0, 0);
      }
  }

  // C/D layout: col=lane&15, row=(lane>>4)*4 + j  [m89 verified]
#pragma unroll
  for (int m = 0; m < 4; ++m) {
    const int row0 = bm + wr + m * 16 + ((l >> 4) << 2);
#pragma unroll
    for (int n = 0; n < 4; ++n) {
      const int col = bn + wc + n * 16 + fr;
      f32x4 v = acc[m][n];
      if constexpr (SPLIT) {
#pragma unroll
        for (int j = 0; j < 4; ++j) {
          const size_t idx = (size_t)(row0 + j) * N + col;
          u16 hh = f2bf(v[j]);
          Chi[idx] = hh;
          Clo[idx] = f2bf(v[j] - bf2f(hh));
        }
      } else {
        float* cp = C + (size_t)row0 * N + col;
#pragma unroll
        for (int j = 0; j < 4; ++j) cp[(size_t)j * N] = v[j];
      }
    }
  }
}

// ---------------------------------------------------------------------------
// Attention v4: 4 query-contexts per block {pr, 15-pr, 16+pr, 31-pr} share one
// staging loop (equal 132 ctx-tiles/block; stages 50..64). Fragment math and
// softmax identical to validated round-5..7 design. V staging = round-4
// conflict-free geometry. Grid 512 = flat 2 blocks/CU.
// ---------------------------------------------------------------------------
#define SC2 0.18033688011112042f /* 0.125 * log2(e) */

struct AttnCtx {
  short8 Qh[2], Ql[2];
  f32x4 acc[4];
  float m_run, l_run;
  int q0w;
};

__device__ __forceinline__ void ctx_init(AttnCtx& C, const u16* __restrict__ qkvh,
                                         const u16* __restrict__ qkvl, size_t base,
                                         int q0w, int g, int q16) {
  C.q0w = q0w;
  const size_t qoff = base + (size_t)(q0w + q16) * (3 * D_MODEL);
#pragma unroll
  for (int dh = 0; dh < 2; ++dh) {
    C.Qh[dh] = *(const short8*)(qkvh + qoff + dh * 32 + g * 8);
    C.Ql[dh] = *(const short8*)(qkvl + qoff + dh * 32 + g * 8);
  }
#pragma unroll
  for (int n = 0; n < 4; ++n) C.acc[n] = f32x4{0.f, 0.f, 0.f, 0.f};
  C.m_run = -1e30f;
  C.l_run = 0.f;
}

// mask+scale (exp2 domain), online-softmax update, P hi/lo store, acc rescale
__device__ __forceinline__ void softmax_store(AttnCtx& C, const f32x4 S[2], int j0,
                                              int g, int q16, char* PhS, char* PlS) {
  const int qg = C.q0w + q16;
  float p[8];
  float mx = -1e30f;
#pragma unroll
  for (int t2 = 0; t2 < 2; ++t2)
#pragma unroll
    for (int j = 0; j < 4; ++j) {
      const int kg = j0 + 16 * t2 + 4 * g + j;
      float s = (kg <= qg) ? S[t2][j] * SC2 : -1e30f;
      p[t2 * 4 + j] = s;
      mx = fmaxf(mx, s);
    }
  mx = fmaxf(mx, __shfl_xor(mx, 16));
  mx = fmaxf(mx, __shfl_xor(mx, 32));
  const float m_new = fmaxf(C.m_run, mx);
  float sum = 0.f;
#pragma unroll
  for (int i = 0; i < 8; ++i) { p[i] = exp2f(p[i] - m_new); sum += p[i]; }
  sum += __shfl_xor(sum, 16);
  sum += __shfl_xor(sum, 32);
  const float alpha = exp2f(C.m_run - m_new);
  C.m_run = m_new;
  C.l_run = C.l_run * alpha + sum;
#pragma unroll
  for (int t2 = 0; t2 < 2; ++t2) {
    u16x4 ph, pl;
#pragma unroll
    for (int j = 0; j < 4; ++j) {
      float v = p[t2 * 4 + j];
      ph[j] = f2bf(v);
      pl[j] = f2bf(v - bf2f(ph[j]));
    }
    const int off = q16 * 80 + (16 * t2 + 4 * g) * 2;
    *(u16x4*)(PhS + off) = ph;
    *(u16x4*)(PlS + off) = pl;
  }
  float al4[4];
#pragma unroll
  for (int j = 0; j < 4; ++j) al4[j] = __shfl(alpha, 4 * g + j);
#pragma unroll
  for (int n = 0; n < 4; ++n) {
    f32x4 t = C.acc[n];
    t[0] *= al4[0]; t[1] *= al4[1]; t[2] *= al4[2]; t[3] *= al4[3];
    C.acc[n] = t;
  }
}

// QK^T for one ctx from shared K fragments, then softmax+P-store
__device__ __forceinline__ void qk_softmax(AttnCtx& C, const short8 (&KAh)[2][2],
                                           const short8 (&KAl)[2][2], int j0, int g,
                                           int q16, char* PhS, char* PlS) {
  f32x4 S[2] = {};
#pragma unroll
  for (int t2 = 0; t2 < 2; ++t2)
#pragma unroll
    for (int dh = 0; dh < 2; ++dh) {
      S[t2] = __builtin_amdgcn_mfma_f32_16x16x32_bf16(KAh[t2][dh], C.Qh[dh], S[t2], 0, 0, 0);
      S[t2] = __builtin_amdgcn_mfma_f32_16x16x32_bf16(KAh[t2][dh], C.Ql[dh], S[t2], 0, 0, 0);
      S[t2] = __builtin_amdgcn_mfma_f32_16x16x32_bf16(KAl[t2][dh], C.Qh[dh], S[t2], 0, 0, 0);
    }
  softmax_store(C, S, j0, g, q16, PhS, PlS);
}

__device__ __forceinline__ void ctx_epilogue(const AttnCtx& C, u16* __restrict__ Ohi,
                                             u16* __restrict__ Olo, int b, int h,
                                             int g, int q16) {
  float inv[4];
#pragma unroll
  for (int j = 0; j < 4; ++j) inv[j] = 1.0f / __shfl(C.l_run, 4 * g + j);
#pragma unroll
  for (int n = 0; n < 4; ++n)
#pragma unroll
    for (int j = 0; j < 4; ++j) {
      const size_t idx =
          ((size_t)b * SEQ + C.q0w + 4 * g + j) * D_MODEL + h * HD + n * 16 + q16;
      const float v = C.acc[n][j] * inv[j];
      const u16 hh = f2bf(v);
      Ohi[idx] = hh;
      Olo[idx] = f2bf(v - bf2f(hh));
    }
}

__launch_bounds__(256, 2)
__global__ void attn_mfma(const u16* __restrict__ qkvh, const u16* __restrict__ qkvl,
                          u16* __restrict__ Ohi, u16* __restrict__ Olo) {
  __shared__ u16 Kh[32][64], Kl[32][64];
  __shared__ u16 Vh[64][40], Vl[64][40];
  __shared__ u16 Ph[4][4][16][40], Pl[4][4][16][40];  // [wave][slot D,C,B,A]

  const int tid = threadIdx.x;
  const int w = tid >> 6, l = tid & 63;
  const int g = l >> 4, q16 = l & 15;
  const int pr = blockIdx.x;  // 0..7
  const int bh = blockIdx.y;
  const int b = bh >> 4, h = bh & 15;
  const size_t base = (size_t)b * SEQ * (3 * D_MODEL) + h * HD;

  char* KhB = (char*)&Kh[0][0];
  char* KlB = (char*)&Kl[0][0];
  char* VhB = (char*)&Vh[0][0];
  char* VlB = (char*)&Vl[0][0];
  char* PhW = (char*)&Ph[w][0][0][0];
  char* PlW = (char*)&Pl[w][0][0][0];

  // contexts by descending key range: D=31-pr, C=16+pr, B=15-pr, A=pr
  AttnCtx D, C, B, A;
  ctx_init(D, qkvh, qkvl, base, (31 - pr) * 64 + w * 16, g, q16);
  ctx_init(C, qkvh, qkvl, base, (16 + pr) * 64 + w * 16, g, q16);
  ctx_init(B, qkvh, qkvl, base, (15 - pr) * 64 + w * 16, g, q16);
  ctx_init(A, qkvh, qkvl, base, pr * 64 + w * 16, g, q16);

  // staging geometry. K: all 256 threads, row sk, 8 cols. V: threads 0..127,
  // round-4 conflict-free transpose geometry (d0=(tid>>3)*4, k0=(tid&7)*4).
  const int sk = tid >> 3, sd0 = (tid & 7) * 8;
  const int vd0 = (tid >> 3) * 4, vk0 = (tid & 7) * 4;
  u16x8 kh_r, kl_r;
  u16x4 vh_r[4], vl_r[4];

  auto loadKV = [&](int j0) {
    const size_t srcK = base + D_MODEL + (size_t)(j0 + sk) * (3 * D_MODEL) + sd0;
    kh_r = *(const u16x8*)(qkvh + srcK);
    kl_r = *(const u16x8*)(qkvl + srcK);
    if (tid < 128) {
      const size_t srcV = base + 2 * D_MODEL + (size_t)(j0 + vk0) * (3 * D_MODEL) + vd0;
#pragma unroll
      for (int r = 0; r < 4; ++r) {
        vh_r[r] = *(const u16x4*)(qkvh + srcV + (size_t)r * (3 * D_MODEL));
        vl_r[r] = *(const u16x4*)(qkvl + srcV + (size_t)r * (3 * D_MODEL));
      }
    }
  };
  auto writeKV = [&]() {
    const int offK = sk * 128 + ((sd0 * 2) ^ ((sk & 7) << 4));  // XOR swizzle
    *(u16x8*)(KhB + offK) = kh_r;
    *(u16x8*)(KlB + offK) = kl_r;
    if (tid < 128) {
#pragma unroll
      for (int j = 0; j < 4; ++j) {  // transpose 4x4 block: V^T[d][k]
        u16x4 th, tl;
        th[0] = vh_r[0][j]; th[1] = vh_r[1][j]; th[2] = vh_r[2][j]; th[3] = vh_r[3][j];
        tl[0] = vl_r[0][j]; tl[1] = vl_r[1][j]; tl[2] = vl_r[2][j]; tl[3] = vl_r[3][j];
        const int off = (vd0 + j) * 80 + vk0 * 2;
        *(u16x4*)(VhB + off) = th;
        *(u16x4*)(VlB + off) = tl;
      }
    }
  };

  const int ktiles = 2 * (31 - pr) + 2;  // 64 - 2*pr
  loadKV(0);
  for (int kt = 0; kt < ktiles; ++kt) {
    const int j0 = kt * 32;
    __syncthreads();                       // prior tile's LDS reads done
    writeKV();                             // regs -> LDS
    __syncthreads();                       // tile visible
    if (kt + 1 < ktiles) loadKV((kt + 1) * 32);  // prefetch next

    const bool actC = j0 <= C.q0w + 15;    // wave-uniform
    const bool actB = j0 <= B.q0w + 15;
    const bool actA = j0 <= A.q0w + 15;

    // ---- shared K A-fragments: lane holds K[key=16*t2+q16][d=dh*32+8g+j]
    short8 KAh[2][2], KAl[2][2];
#pragma unroll
    for (int t2 = 0; t2 < 2; ++t2)
#pragma unroll
      for (int dh = 0; dh < 2; ++dh) {
        const int off = (16 * t2 + q16) * 128 + ((dh * 64 + g * 16) ^ ((q16 & 7) << 4));
        KAh[t2][dh] = *(const short8*)(KhB + off);
        KAl[t2][dh] = *(const short8*)(KlB + off);
      }

    // ---- QK^T + softmax per active ctx (slots: D=0,C=1,B=2,A=3)
    qk_softmax(D, KAh, KAl, j0, g, q16, PhW, PlW);
    if (actC) qk_softmax(C, KAh, KAl, j0, g, q16, PhW + 1280, PlW + 1280);
    if (actB) qk_softmax(B, KAh, KAl, j0, g, q16, PhW + 2560, PlW + 2560);
    if (actA) qk_softmax(A, KAh, KAl, j0, g, q16, PhW + 3840, PlW + 3840);

    // ---- P fragments
    const int pf = q16 * 80 + g * 16;
    short8 PDh = *(const short8*)(PhW + pf);
    short8 PDl = *(const short8*)(PlW + pf);
    short8 PCh, PCl, PBh, PBl, PAh, PAl;
    if (actC) { PCh = *(const short8*)(PhW + 1280 + pf); PCl = *(const short8*)(PlW + 1280 + pf); }
    if (actB) { PBh = *(const short8*)(PhW + 2560 + pf); PBl = *(const short8*)(PlW + 2560 + pf); }
    if (actA) { PAh = *(const short8*)(PhW + 3840 + pf); PAl = *(const short8*)(PlW + 3840 + pf); }

    // ---- PV: shared V^T B-fragments per d-tile n
#pragma unroll
    for (int n = 0; n < 4; ++n) {
      const int off = (16 * n + q16) * 80 + g * 16;
      const short8 VBh = *(const short8*)(VhB + off);
      const short8 VBl = *(const short8*)(VlB + off);
      D.acc[n] = __builtin_amdgcn_mfma_f32_16x16x32_bf16(PDh, VBh, D.acc[n], 0, 0, 0);
      D.acc[n] = __builtin_amdgcn_mfma_f32_16x16x32_bf16(PDh, VBl, D.acc[n], 0, 0, 0);
      D.acc[n] = __builtin_amdgcn_mfma_f32_16x16x32_bf16(PDl, VBh, D.acc[n], 0, 0, 0);
      if (actC) {
        C.acc[n] = __builtin_amdgcn_mfma_f32_16x16x32_bf16(PCh, VBh, C.acc[n], 0, 0, 0);
        C.acc[n] = __builtin_amdgcn_mfma_f32_16x16x32_bf16(PCh, VBl, C.acc[n], 0, 0, 0);
        C.acc[n] = __builtin_amdgcn_mfma_f32_16x16x32_bf16(PCl, VBh, C.acc[n], 0, 0, 0);
      }
      if (actB) {
        B.acc[n] = __builtin_amdgcn_mfma_f32_16x16x32_bf16(PBh, VBh, B.acc[n], 0, 0, 0);
        B.acc[n] = __builtin_amdgcn_mfma_f32_16x16x32_bf16(PBh, VBl, B.acc[n], 0, 0, 0);
        B.acc[n] = __builtin_amdgcn_mfma_f32_16x16x32_bf16(PBl, VBh, B.acc[n], 0, 0, 0);
      }
      if (actA) {
        A.acc[n] = __builtin_amdgcn_mfma_f32_16x16x32_bf16(PAh, VBh, A.acc[n], 0, 0, 0);
        A.acc[n] = __builtin_amdgcn_mfma_f32_16x16x32_bf16(PAh, VBl, A.acc[n], 0, 0, 0);
        A.acc[n] = __builtin_amdgcn_mfma_f32_16x16x32_bf16(PAl, VBh, A.acc[n], 0, 0, 0);
      }
    }
  }

  ctx_epilogue(D, Ohi, Olo, b, h, g, q16);
  ctx_epilogue(C, Ohi, Olo, b, h, g, q16);
  ctx_epilogue(B, Ohi, Olo, b, h, g, q16);
  ctx_epilogue(A, Ohi, Olo, b, h, g, q16);
}

// ---------------------------------------------------------------------------
extern "C" void kernel_launch(void* const* d_in, const int* in_sizes, int n_in,
                              void* d_out, int out_size, void* d_ws, size_t ws_size,
                              hipStream_t stream) {
  const float* x    = (const float*)d_in[0];   // [4,2048,1024]
  const float* Wqkv = (const float*)d_in[1];   // [3072,1024]
  const float* Wout = (const float*)d_in[2];   // [1024,1024]
  float* out = (float*)d_out;                  // [4,2048,1024]

  const int M = BATCH * SEQ;                   // 8192
  const int N1 = 3 * D_MODEL;                  // 3072
  const size_t MB = 1024 * 1024;

  // workspace layout (144 MB, with aliasing):
  char* ws = (char*)d_ws;
  u16* qkvh = (u16*)(ws);                      // [0,48)   MB
  u16* qkvl = (u16*)(ws + 48 * MB);            // [48,96)
  u16* xhi  = (u16*)(ws + 96 * MB);            // [96,112)
  u16* xlo  = (u16*)(ws + 112 * MB);           // [112,128)
  u16* whi  = (u16*)(ws + 128 * MB);           // [128,134)
  u16* wlo  = (u16*)(ws + 134 * MB);           // [134,140)
  u16* ohi  = (u16*)(ws + 140 * MB);           // [140,142)
  u16* olo  = (u16*)(ws + 142 * MB);           // [142,144)
  // attention output hi/lo alias xhi/xlo (dead after GEMM1):
  u16* ahi  = (u16*)(ws + 96 * MB);
  u16* alo  = (u16*)(ws + 112 * MB);

  // 1) split inputs to bf16 hi/lo
  split_hl<<<2048, 256, 0, stream>>>(x,    xhi, xlo, M * D_MODEL / 4);
  split_hl<<<2048, 256, 0, stream>>>(Wqkv, whi, wlo, N1 * D_MODEL / 4);
  split_hl<<<1024, 256, 0, stream>>>(Wout, ohi, olo, D_MODEL * D_MODEL / 4);

  // 2) qkv(hi/lo) = x @ Wqkv^T   (emit split directly from fp32 accumulator)
  gemm_nt_bf16x3<1><<<dim3(N1 / 128, M / 128), 256, 0, stream>>>(
      xhi, xlo, whi, wlo, nullptr, qkvh, qkvl, M, N1, D_MODEL);

  // 3) causal MFMA flash attention (4 contexts/block, equal-runtime blocks)
  attn_mfma<<<dim3(8, BATCH * NH), 256, 0, stream>>>(qkvh, qkvl, ahi, alo);

  // 4) out = attn @ Wout^T  (fp32 out)
  gemm_nt_bf16x3<0><<<dim3(D_MODEL / 128, M / 128), 256, 0, stream>>>(
      ahi, alo, ohi, olo, out, nullptr, nullptr, M, D_MODEL, D_MODEL);
}